// Round 14
// baseline (354.435 us; speedup 1.0000x reference)
//
#include <hip/hip_runtime.h>
#include <hip/hip_bf16.h>

#define NNODES 50000
#define NEDGES 600000
#define NB 196     // ceil(NNODES/256)
#define NBKT 196   // coarse buckets (dst >> 8)
#define SB 192     // edge-pass blocks (hist + count + scatter)
#define SCH (NEDGES / SB)   // 3125 edges per block (exact)
#define STRIPS 782 // ceil(NNODES/64) row strips for conv

typedef short vs8 __attribute__((ext_vector_type(8)));
typedef float floatx4 __attribute__((ext_vector_type(4)));

__device__ __forceinline__ float us2f(unsigned short u) {
    unsigned int x = ((unsigned int)u) << 16;
    float f;
    __builtin_memcpy(&f, &x, 4);
    return f;
}
__device__ __forceinline__ unsigned short f2us(float f) {
    unsigned int x;
    __builtin_memcpy(&x, &f, 4);
    unsigned int r = x + 0x7fffu + ((x >> 16) & 1u);  // RNE
    return (unsigned short)(r >> 16);
}
__device__ __forceinline__ float ldf(const void* p, int i, int ff) {
    if (ff) return us2f(((const unsigned short*)p)[i]);
    return ((const float*)p)[i];
}
// inline dtype detection; every wave computes it from the first 256B of the
// edge list / feature — L2-hit broadcast, wave-uniform result.
__device__ __forceinline__ int detect_iflag(const int* ei) {
    int lane = threadIdx.x & 63;
    int odd1 = ei[2 * lane + 1];
    int odd2 = ei[128 + 2 * lane + 1];
    unsigned long long nz = __ballot(odd1 != 0 || odd2 != 0);
    return (nz == 0ULL) ? 1 : 0;
}
__device__ __forceinline__ int detect_fflag(const unsigned int* fw) {
    int lane = threadIdx.x & 63;
    unsigned int e = (fw[lane] >> 7) & 0xffu;
    unsigned long long h = __ballot(e > 100u && e < 160u);
    return (__popcll(h) > 40) ? 1 : 0;  // 1 = bf16 storage
}
// nontemporal 8B load of an (src, weight-bits) pair
__device__ __forceinline__ int2 ldnt_sw(const int2* p) {
    unsigned long long v =
        __builtin_nontemporal_load(reinterpret_cast<const unsigned long long*>(p));
    int2 r;
    r.x = (int)(unsigned int)(v & 0xffffffffULL);
    r.y = (int)(unsigned int)(v >> 32);
    return r;
}
// async global->LDS, 16B per lane; LDS dest = wave-uniform base + lane*16
__device__ __forceinline__ void gload_lds16(const unsigned short* g, unsigned short* l) {
    __builtin_amdgcn_global_load_lds(
        (const __attribute__((address_space(1))) unsigned int*)g,
        (__attribute__((address_space(3))) unsigned int*)l, 16, 0, 0);
}
// accumulate one weighted bf16x8 row chunk
__device__ __forceinline__ void accum8(float w, uint4 u, float& a0, float& a1,
                                       float& a2, float& a3, float& a4, float& a5,
                                       float& a6, float& a7) {
    a0 += w * us2f((unsigned short)(u.x & 0xffffu));
    a1 += w * us2f((unsigned short)(u.x >> 16));
    a2 += w * us2f((unsigned short)(u.y & 0xffffu));
    a3 += w * us2f((unsigned short)(u.y >> 16));
    a4 += w * us2f((unsigned short)(u.z & 0xffffu));
    a5 += w * us2f((unsigned short)(u.z >> 16));
    a6 += w * us2f((unsigned short)(u.w & 0xffffu));
    a7 += w * us2f((unsigned short)(u.w >> 16));
}

// canonicalize feature -> bf16 (16B/thread) + batch convert + psum zero
__global__ void k_featb(const void* src, const int* ei, const int* pb,
                        int* b32, float* psum, unsigned short* dst) {
    int i = blockIdx.x * 256 + threadIdx.x;
    int f = detect_iflag(ei);
    int ff = detect_fflag((const unsigned int*)src);
    if (i < NNODES) b32[i] = pb[((size_t)i) << f];
    if (i < 128 * 384) psum[i] = 0.f;
    if (i >= NNODES * 128 / 8) return;
    if (ff) {
        reinterpret_cast<uint4*>(dst)[i] = reinterpret_cast<const uint4*>(src)[i];
    } else {
        const float4* fs = reinterpret_cast<const float4*>(src);
        float4 a = fs[2 * i], b = fs[2 * i + 1];
        uint4 o;
        o.x = (unsigned int)f2us(a.x) | ((unsigned int)f2us(a.y) << 16);
        o.y = (unsigned int)f2us(a.z) | ((unsigned int)f2us(a.w) << 16);
        o.z = (unsigned int)f2us(b.x) | ((unsigned int)f2us(b.y) << 16);
        o.w = (unsigned int)f2us(b.z) | ((unsigned int)f2us(b.w) << 16);
        reinterpret_cast<uint4*>(dst)[i] = o;
    }
}

// ---- merged edge pass #1: out-degree histogram + coarse dst counts ----
__global__ __launch_bounds__(256) void k_deghist(const int* ei,
                                                 unsigned int* degpart, int* cntT) {
    __shared__ unsigned int h[25000];  // 100 KB
    __shared__ int c[NBKT];
    int t = threadIdx.x, blk = blockIdx.x;
    int f = detect_iflag(ei);
    for (int i = t; i < 25000; i += 256) h[i] = 0u;
    if (t < NBKT) c[t] = 0;
    __syncthreads();
    int e0 = blk * SCH;
    for (int j = t; j < SCH; j += 256) {
        int e = e0 + j;
        int s = ei[((size_t)e) << f];
        int d = ei[((size_t)(NEDGES + e)) << f];
        atomicAdd(&h[s >> 1], (s & 1) ? 65536u : 1u);
        atomicAdd(&c[d >> 8], 1);
    }
    __syncthreads();
    unsigned int* dp = degpart + (size_t)blk * 25000;
    for (int i = t; i < 25000; i += 256) dp[i] = h[i];
    if (t < NBKT) cntT[t * SB + blk] = c[t];
}

// merged: per-bucket parallel prefix (blocks 0..195) + degree reduce ->
// dinv (blocks 196..293). Independent work, one launch.
__global__ void k_mid(const unsigned int* degpart, float* dinv, int* cntT, int* btot) {
    int bid = blockIdx.x, t = threadIdx.x;
    if (bid < NBKT) {
        __shared__ int sh[256];
        int b = bid;
        int v = (t < SB) ? cntT[b * SB + t] : 0;
        sh[t] = v;
        __syncthreads();
        for (int off = 1; off < 256; off <<= 1) {
            int x = (t >= off) ? sh[t - off] : 0;
            __syncthreads();
            sh[t] += x;
            __syncthreads();
        }
        if (t < SB) cntT[b * SB + t] = sh[t] - v;  // exclusive prefix
        if (t == 255) btot[b] = sh[255];           // bucket total
    } else {
        int i = (bid - NBKT) * 256 + t;  // word index
        if (i >= 25000) return;
        unsigned int lo = 0, hi = 0;
        for (int b = 0; b < SB; ++b) {
            unsigned int p = degpart[(size_t)b * 25000 + i];
            lo += p & 0xffffu;
            hi += p >> 16;
        }
        dinv[2 * i] = lo ? rsqrtf((float)lo) : 0.f;
        dinv[2 * i + 1] = hi ? rsqrtf((float)hi) : 0.f;
    }
}

// one-block scan over 196 bucket totals -> gbase; pcnt binary searches.
__global__ void k_bscan2(const int* btot, int* gbase, const int* batch32,
                         int* pcnt, int* rowptr) {
    __shared__ int sh[256];
    int t = threadIdx.x;
    int v = (t < NBKT) ? btot[t] : 0;
    sh[t] = v;
    __syncthreads();
    for (int off = 1; off < 256; off <<= 1) {
        int x = (t >= off) ? sh[t - off] : 0;
        __syncthreads();
        sh[t] += x;
        __syncthreads();
    }
    if (t < NBKT) gbase[t] = sh[t] - v;
    if (t == 0) {
        gbase[NBKT] = NEDGES;
        rowptr[NNODES] = NEDGES;
    }
    if (t < 128) {
        int g = t;
        int lo = 0, hi = NNODES;
        while (lo < hi) { int mid = (lo + hi) >> 1; if (batch32[mid] < g) lo = mid + 1; else hi = mid; }
        int start = lo;
        hi = NNODES;
        while (lo < hi) { int mid = (lo + hi) >> 1; if (batch32[mid] <= g) lo = mid + 1; else hi = mid; }
        pcnt[g] = lo - start;
    }
}

// scatter edges into coarse buckets; cursor base = gbase + per-block prefix
__global__ void k_scat(const int* ei, const float* dinv,
                       const int* gbase, const int* cntT, int2* bkt) {
    __shared__ int cur[NBKT];
    int t = threadIdx.x, blk = blockIdx.x;
    int f = detect_iflag(ei);
    if (t < NBKT) cur[t] = gbase[t] + cntT[t * SB + blk];
    __syncthreads();
    int e0 = blk * SCH;
    for (int j = t; j < SCH; j += 256) {
        int e = e0 + j;
        int s = ei[((size_t)e) << f];
        int d = ei[((size_t)(NEDGES + e)) << f];
        float w = -dinv[s] * dinv[d];
        int slot = atomicAdd(&cur[d >> 8], 1);
        int wb;
        __builtin_memcpy(&wb, &w, 4);
        int2 v;
        v.x = s | ((d & 255) << 16);
        v.y = wb;
        bkt[slot] = v;
    }
}

// fine pass: one block per bucket; LDS 256-bin histogram + scan gives
// rowptr directly; LDS cursors give each edge its final CSR slot.
__global__ void k_csr(const int2* bkt, const int* gbase, int* rowptr, int2* csr_sw) {
    __shared__ int hist[256], scan[256], cur[256];
    int t = threadIdx.x, b = blockIdx.x;
    int beg = gbase[b], end = gbase[b + 1];
    int n = end - beg;
    hist[t] = 0;
    __syncthreads();
    for (int i = t; i < n; i += 256) {
        int bin = (bkt[beg + i].x >> 16) & 255;
        atomicAdd(&hist[bin], 1);
    }
    __syncthreads();
    int h = hist[t];
    scan[t] = h;
    __syncthreads();
    for (int off = 1; off < 256; off <<= 1) {
        int x = (t >= off) ? scan[t - off] : 0;
        __syncthreads();
        scan[t] += x;
        __syncthreads();
    }
    int excl = scan[t] - h;
    int node = b * 256 + t;
    if (node < NNODES) rowptr[node] = beg + excl;
    cur[t] = excl;
    __syncthreads();
    for (int i = t; i < n; i += 256) {
        int2 p = bkt[beg + i];
        int bin = (p.x >> 16) & 255;
        int slot = atomicAdd(&cur[bin], 1);
        int2 v;
        v.x = p.x & 0xffff;
        v.y = p.y;
        csr_sw[beg + slot] = v;
    }
}

// ALL weight prep in one launch (410624 elements)
__global__ void k_prepall(const void* W1, const void* W2, const void* b1, const void* b2,
                          const void* f1w, const void* f1b, const void* f2w, const void* f2b,
                          const unsigned int* fw, unsigned short* W1t, unsigned short* W2t,
                          float* b1f, float* b2f, float* f1wf, float* f1bf,
                          float* f2wf, float* f2bf) {
    int i = blockIdx.x * 256 + threadIdx.x;
    int ff = detect_fflag(fw);
    if (i < 49152) {
        int c = i >> 13;
        int rem = i & 8191;
        int cr = rem >> 6;
        int rem2 = rem & 63;
        int g = rem2 >> 3, j = rem2 & 7;
        int k = c * 64 + ((g ^ (cr & 7)) << 3) + j;
        int n = cr;
        float v;
        if (k < 128) v = ldf(W1, k * 128 + n, ff) - ldf(W1, (256 + k) * 128 + n, ff);
        else if (k < 256) v = ldf(W1, k * 128 + n, ff);
        else v = 2.f * ldf(W1, k * 128 + n, ff);
        W1t[i] = f2us(v);
        return;
    }
    i -= 49152;
    if (i < 98304) {
        int ct = i / 49152;
        int rem = i % 49152;
        int c = rem >> 13;
        int rem1 = rem & 8191;
        int cr = rem1 >> 6;
        int rem2 = rem1 & 63;
        int g = rem2 >> 3, j = rem2 & 7;
        int k = c * 64 + ((g ^ (cr & 7)) << 3) + j;
        int n = ct * 128 + cr;
        float v;
        if (k < 128) v = ldf(W2, k * 256 + n, ff) - ldf(W2, (256 + k) * 256 + n, ff);
        else if (k < 256) v = ldf(W2, k * 256 + n, ff);
        else v = 2.f * ldf(W2, k * 256 + n, ff);
        W2t[i] = f2us(v);
        return;
    }
    i -= 98304;
    if (i < 196608) { f1wf[i] = ldf(f1w, i, ff); return; }
    i -= 196608;
    if (i < 65536) { f2wf[i] = ldf(f2w, i, ff); return; }
    i -= 65536;
    if (i < 512) { f1bf[i] = ldf(f1b, i, ff); return; }
    i -= 512;
    if (i < 256) { b2f[i] = ldf(b2, i, ff); return; }
    i -= 256;
    if (i < 128) { b1f[i] = ldf(b1, i, ff); return; }
    i -= 128;
    if (i < 128) f2bf[i] = ldf(f2b, i, ff);
}

// out[n,:] = sum_{e into n} w_e * X[src_e,:]   (pure gather)
// UNIFORM clamped 12-deep loop at (256,5): rows-in-flight/CU 192 -> 240
// (R10 law: line concurrency is the knob for coalesced gathers). Live set
// ~100 VGPR fits the 102 cap (5 waves/SIMD); mean degree 12 -> most rows
// finish in ONE iteration. OOB slots clamp index to end-1 (cache hit) and
// zero the weight.
__global__ __launch_bounds__(256, 5) void k_prop(const unsigned short* X,
                                                 const int* rowptr, const int2* csr_sw,
                                                 unsigned short* out) {
    int wvid = (blockIdx.x * blockDim.x + threadIdx.x) >> 6;
    int lane = threadIdx.x & 63;
    int q = lane >> 4;
    int ln = lane & 15;
    int node = wvid * 4 + q;
    if (node >= NNODES) return;
    int fo = ln * 8;  // short offset, 16 B per lane
    int beg = rowptr[node], end = rowptr[node + 1];
    float a0 = 0.f, a1 = 0.f, a2 = 0.f, a3 = 0.f;
    float a4 = 0.f, a5 = 0.f, a6 = 0.f, a7 = 0.f;
    for (int j = beg; j < end; j += 12) {
        int last = end - 1;
        int2 e[12];
        uint4 u[12];
        float w[12];
#pragma unroll
        for (int k = 0; k < 12; ++k) {
            int t = j + k;
            e[k] = ldnt_sw(csr_sw + (t < end ? t : last));
        }
#pragma unroll
        for (int k = 0; k < 12; ++k)
            u[k] = *reinterpret_cast<const uint4*>(X + (size_t)e[k].x * 128 + fo);
#pragma unroll
        for (int k = 0; k < 12; ++k) {
            float wk;
            __builtin_memcpy(&wk, &e[k].y, 4);
            w[k] = (k == 0 || j + k < end) ? wk : 0.f;
        }
#pragma unroll
        for (int k = 0; k < 12; ++k)
            accum8(w[k], u[k], a0, a1, a2, a3, a4, a5, a6, a7);
    }
    uint4 ov;
    ov.x = (unsigned int)f2us(a0) | ((unsigned int)f2us(a1) << 16);
    ov.y = (unsigned int)f2us(a2) | ((unsigned int)f2us(a3) << 16);
    ov.z = (unsigned int)f2us(a4) | ((unsigned int)f2us(a5) << 16);
    ov.w = (unsigned int)f2us(a6) | ((unsigned int)f2us(a7) << 16);
    *reinterpret_cast<uint4*>(out + (size_t)node * 128 + fo) = ov;
}

// ---- MFMA conv GEMM: 64x128 tile, 3 blocks/CU; pool blocks first ----
template <int POOL, int CT>
__global__ __launch_bounds__(512, 6) void k_convg(
    const unsigned short* seg0, const unsigned short* seg1, const unsigned short* seg2,
    const unsigned short* Wt, const float* bias, unsigned short* out,
    const int* batch32, float* psum, const unsigned short* featX) {
    __shared__ __align__(16) unsigned short a_lds[2][4096];  // 8 KB x2 (64r x 64k)
    __shared__ __align__(16) unsigned short b_lds[2][8192];  // 16 KB x2 (128c x 64k)
    __shared__ float sh_ps[POOL ? 1024 : 1];
    int tid = threadIdx.x;
    int bid = blockIdx.x;
    if (POOL) {
        if (bid < 196) {  // featb pooling blocks FIRST (overlap, not tail)
            int pb = bid;
            int col = tid & 127, qq = tid >> 7;  // qq 0..3, 4x64 = 256 nodes/block
            int nbeg = pb * 256 + qq * 64;
            if (nbeg < NNODES) {
                int nend = nbeg + 64;
                if (nend > NNODES) nend = NNODES;
                float run = 0.f;
                int curg = batch32[nbeg];
                for (int n = nbeg; n < nend; ++n) {
                    int g = batch32[n];
                    if (g != curg) {
                        atomicAdd(&psum[curg * 384 + 256 + col], run);
                        run = 0.f;
                        curg = g;
                    }
                    run += us2f(featX[(size_t)n * 128 + col]);
                }
                atomicAdd(&psum[curg * 384 + 256 + col], run);
            }
            return;
        }
        bid -= 196;
    }
    // XCD-grouped supertiles over 782 strips of 64 rows; ct-major within.
    int grp = 8 * CT;
    int main_blocks = 97 * grp;  // strips 0..775
    int r, ct;
    if (bid < main_blocks) {
        int g = bid / grp;
        int rem = bid - g * grp;
        ct = rem >> 3;
        r = g * 8 + (rem & 7);
    } else {
        int t = bid - main_blocks;  // tail strips 776..781
        r = 776 + (CT == 1 ? t : t % 6);
        ct = (CT == 1) ? 0 : t / 6;
    }
    int r0 = r * 64;
    const unsigned short* segs[3] = {seg0, seg1, seg2};
    int wv = tid >> 6, lane = tid & 63;
    int wm = wv >> 2, wn = wv & 3;  // 2M x 4N waves; wave tile 32r x 32c
    int m = lane & 15, kq = lane >> 4;
    if (POOL) { sh_ps[tid] = 0.f; sh_ps[tid + 512] = 0.f; }

    // stage K-step c: A = 8 chunks of 1KB (1/wave), B = 16 chunks (2/wave)
    auto STAGE = [&](int buf, int c) {
        const unsigned short* S = segs[c >> 1];
        int h = c & 1;
        {
            int q = wv;                       // A chunk 0..7
            int rl = q * 8 + (lane >> 3);     // local row 0..63
            int g = lane & 7;                 // granule 0..7
            int rowg = r0 + rl;
            if (rowg >= NNODES) rowg = NNODES - 1;
            gload_lds16(S + (size_t)rowg * 128 + h * 64 + ((g ^ (rl & 7)) << 3),
                        &a_lds[buf][q * 512]);
        }
#pragma unroll
        for (int p = 0; p < 2; ++p) {
            int q = wv * 2 + p;
            gload_lds16(Wt + (size_t)(ct * 6 + c) * 8192 + q * 512 + (lane << 3),
                        &b_lds[buf][q * 512]);
        }
    };

    floatx4 acc[2][2];
#pragma unroll
    for (int mt = 0; mt < 2; ++mt)
#pragma unroll
        for (int nt = 0; nt < 2; ++nt) {
            acc[mt][nt][0] = 0.f; acc[mt][nt][1] = 0.f;
            acc[mt][nt][2] = 0.f; acc[mt][nt][3] = 0.f;
        }

    STAGE(0, 0);
    __syncthreads();
    int buf = 0;
#pragma unroll
    for (int c = 0; c < 6; ++c) {
        if (c < 5) STAGE(buf ^ 1, c + 1);
        vs8 af[2], bfr[2];
#pragma unroll
        for (int kf = 0; kf < 2; ++kf) {
            int G = kf * 4 + kq;
#pragma unroll
            for (int mt = 0; mt < 2; ++mt) {
                int row = wm * 32 + mt * 16 + m;
                af[mt] = *reinterpret_cast<const vs8*>(
                    &a_lds[buf][row * 64 + ((G ^ (row & 7)) << 3)]);
            }
#pragma unroll
            for (int nt = 0; nt < 2; ++nt) {
                int cl = wn * 32 + nt * 16 + m;
                bfr[nt] = *reinterpret_cast<const vs8*>(
                    &b_lds[buf][cl * 64 + ((G ^ (cl & 7)) << 3)]);
            }
#pragma unroll
            for (int mt = 0; mt < 2; ++mt)
#pragma unroll
                for (int nt = 0; nt < 2; ++nt)
                    acc[mt][nt] = __builtin_amdgcn_mfma_f32_16x16x32_bf16(
                        af[mt], bfr[nt], acc[mt][nt], 0, 0, 0);
        }
        if (c < 5) {
            __syncthreads();
            buf ^= 1;
        }
    }

    if (POOL == 0) {
#pragma unroll
        for (int mt = 0; mt < 2; ++mt) {
            int rbase = r0 + wm * 32 + mt * 16 + kq * 4;
#pragma unroll
            for (int nt = 0; nt < 2; ++nt) {
                int col = wn * 32 + nt * 16 + m;
                float bv = bias[col];
#pragma unroll
                for (int i = 0; i < 4; ++i) {
                    int rw = rbase + i;
                    if (rw < NNODES) {
                        float v = acc[mt][nt][i] + bv;
                        v = v > 0.f ? v : 0.f;
                        out[(size_t)rw * 128 + col] = f2us(v);
                    }
                }
            }
        }
    } else {
        int g0 = batch32[r0];  // min graph in block (batch sorted)
#pragma unroll
        for (int mt = 0; mt < 2; ++mt) {
            int rbase = r0 + wm * 32 + mt * 16 + kq * 4;
            int gid[4];
#pragma unroll
            for (int i = 0; i < 4; ++i) {
                int rw = rbase + i;
                gid[i] = rw < NNODES ? batch32[rw] : -1;
            }
#pragma unroll
            for (int nt = 0; nt < 2; ++nt) {
                int cl = wn * 32 + nt * 16 + m;
                int col = ct * 128 + cl;
                float bv = bias[col];
                float run = 0.f;
                int curg = -1;
#pragma unroll
                for (int i = 0; i < 4; ++i) {
                    int g = gid[i];
                    if (g < 0) break;
                    float v = acc[mt][nt][i] + bv;
                    v = v > 0.f ? v : 0.f;
                    if (g != curg) {
                        if (curg >= 0) {
                            int gl = curg - g0;
                            if (gl >= 0 && gl < 8) atomicAdd(&sh_ps[gl * 128 + cl], run);
                            else atomicAdd(&psum[curg * 384 + col], run);
                        }
                        curg = g;
                        run = 0.f;
                    }
                    run += v;
                }
                if (curg >= 0) {
                    int gl = curg - g0;
                    if (gl >= 0 && gl < 8) atomicAdd(&sh_ps[gl * 128 + cl], run);
                    else atomicAdd(&psum[curg * 384 + col], run);
                }
            }
        }
        __syncthreads();
        for (int idx = tid; idx < 1024; idx += 512) {
            int gl = idx >> 7, cl = idx & 127;
            float v = sh_ps[idx];
            int gg = g0 + gl;
            if (v != 0.f && gg < 128) atomicAdd(&psum[(size_t)gg * 384 + ct * 128 + cl], v);
        }
    }
}

// FC1, parallelism-first: 512 blocks = (graph, 128-col slice), k split in
// halves of 192 -> per-thread chain 192 iters, LDS pair-reduce.
__global__ void k_fc1(const float* psum, const int* pcnt, const float* w,
                      const float* b, float* h) {
    __shared__ float ps[256];
    int g = blockIdx.x >> 2, slice = blockIdx.x & 3;
    int tid = threadIdx.x;
    int col = slice * 128 + (tid & 127);
    int half = tid >> 7;
    float a = 0.f;
    int k0 = half * 192;
    for (int k = k0; k < k0 + 192; ++k)
        a += psum[g * 384 + k] * w[k * 512 + col];
    ps[tid] = a;
    __syncthreads();
    if (tid < 128) {
        int c = pcnt[g];
        float inv = 1.f / (float)(c > 0 ? c : 1);
        float v = (ps[tid] + ps[tid + 128]) * inv + b[col];
        h[g * 512 + col] = v > 0.f ? v : 0.f;
    }
}

// FC2: 256 blocks = (graph, 64-col slice), k split in quarters of 128 ->
// chain 128 iters, LDS 4-way reduce. Carries the harness identifier name.
__global__ void ChebModel_74380243632480_kernel(
    const float* h, const float* w, const float* b, const unsigned int* fw,
    void* out) {
    __shared__ float ps[256];
    int g = blockIdx.x >> 1, slice = blockIdx.x & 1;
    int tid = threadIdx.x;
    int ff = detect_fflag(fw);
    int col = slice * 64 + (tid & 63);
    int qq = tid >> 6;
    float a = 0.f;
    int k0 = qq * 128;
    for (int k = k0; k < k0 + 128; ++k)
        a += h[g * 512 + k] * w[k * 128 + col];
    ps[tid] = a;
    __syncthreads();
    if (tid < 64) {
        float v = ps[tid] + ps[tid + 64] + ps[tid + 128] + ps[tid + 192] + b[col];
        if (ff) ((unsigned short*)out)[g * 128 + col] = f2us(v);
        else ((float*)out)[g * 128 + col] = v;
    }
}

extern "C" void kernel_launch(void* const* d_in, const int* in_sizes, int n_in,
                              void* d_out, int out_size, void* d_ws, size_t ws_size,
                              hipStream_t stream) {
    const void* feature = d_in[0];
    const int* edge_index = (const int*)d_in[1];
    const int* batch = (const int*)d_in[2];
    const void* W1 = d_in[3];
    const void* b1 = d_in[4];
    const void* W2 = d_in[5];
    const void* b2 = d_in[6];
    const void* fc1w = d_in[7];
    const void* fc1b = d_in[8];
    const void* fc2w = d_in[9];
    const void* fc2b = d_in[10];

    char* ws = (char*)d_ws;
    size_t off = 0;
    int* rowptr = (int*)(ws + off); off += ((size_t)(NNODES + 1) * 4 + 255) & ~(size_t)255;
    float* dinv = (float*)(ws + off); off += ((size_t)NNODES * 4 + 255) & ~(size_t)255;
    int* batch32 = (int*)(ws + off); off += ((size_t)NNODES * 4 + 255) & ~(size_t)255;
    int* gbase = (int*)(ws + off); off += 1024;
    int* cntT = (int*)(ws + off); off += ((size_t)SB * NBKT * 4 + 255) & ~(size_t)255;
    int* btot = (int*)(ws + off); off += 1024;
    int2* csr_sw = (int2*)(ws + off); off += ((size_t)NEDGES * 8 + 255) & ~(size_t)255;
    unsigned short* featb = (unsigned short*)(ws + off); off += ((size_t)NNODES * 128 * 2 + 255) & ~(size_t)255;
    unsigned short* T1 = (unsigned short*)(ws + off); off += ((size_t)NNODES * 128 * 2 + 255) & ~(size_t)255;
    unsigned short* T2 = (unsigned short*)(ws + off); off += ((size_t)NNODES * 128 * 2 + 255) & ~(size_t)255;
    unsigned short* gx1 = (unsigned short*)(ws + off); off += ((size_t)NNODES * 128 * 2 + 255) & ~(size_t)255;
    unsigned short* W1t = (unsigned short*)(ws + off); off += ((size_t)49152 * 2 + 255) & ~(size_t)255;
    unsigned short* W2t = (unsigned short*)(ws + off); off += ((size_t)98304 * 2 + 255) & ~(size_t)255;
    float* b1f = (float*)(ws + off); off += 1024;
    float* b2f = (float*)(ws + off); off += 1024;
    float* fc1wf = (float*)(ws + off); off += ((size_t)196608 * 4 + 255) & ~(size_t)255;
    float* fc1bf = (float*)(ws + off); off += 2048;
    float* fc2wf = (float*)(ws + off); off += ((size_t)65536 * 4 + 255) & ~(size_t)255;
    float* fc2bf = (float*)(ws + off); off += 1024;
    float* psum = (float*)(ws + off); off += ((size_t)128 * 384 * 4 + 255) & ~(size_t)255;
    int* pcnt = (int*)(ws + off); off += 1024;
    float* hbuf = (float*)(ws + off); off += ((size_t)128 * 512 * 4 + 255) & ~(size_t)255;

    // sort scratch aliases the T1/T2/gx1 feature buffers (all first written
    // only after preprocessing is fully done):
    int2* bkt = (int2*)T1;                       // 4.8 MB <= 12.8 MB
    unsigned int* degpart = (unsigned int*)T2;   // SB*25000*4 = 19.2 MB <= T2+gx1 (25.6 MB)

    k_featb<<<(NNODES * 128 / 8 + 255) / 256, 256, 0, stream>>>(
        feature, edge_index, batch, batch32, psum, featb);
    k_deghist<<<SB, 256, 0, stream>>>(edge_index, degpart, cntT);
    k_mid<<<NBKT + (25000 + 255) / 256, 256, 0, stream>>>(degpart, dinv, cntT, btot);
    k_bscan2<<<1, 256, 0, stream>>>(btot, gbase, batch32, pcnt, rowptr);
    k_scat<<<SB, 256, 0, stream>>>(edge_index, dinv, gbase, cntT, bkt);
    k_csr<<<NBKT, 256, 0, stream>>>(bkt, gbase, rowptr, csr_sw);
    k_prepall<<<(410624 + 255) / 256, 256, 0, stream>>>(
        W1, W2, b1, b2, fc1w, fc1b, fc2w, fc2b, (const unsigned int*)feature,
        W1t, W2t, b1f, b2f, fc1wf, fc1bf, fc2wf, fc2bf);

    int pb = ((NNODES + 3) / 4 * 64 + 255) / 256;  // 3125 blocks, 4 nodes/wave
    // conv1: T1 = P(featb), T2 = P(T1); gx1 = relu([featb|T1|T2] @ foldedW1 + b1)
    k_prop<<<pb, 256, 0, stream>>>(featb, rowptr, csr_sw, T1);
    k_prop<<<pb, 256, 0, stream>>>(T1, rowptr, csr_sw, T2);
    k_convg<0, 1><<<97 * 8 + 6, 512, 0, stream>>>(featb, T1, T2, W1t, b1f, gx1,
                                                  (const int*)0, (float*)0,
                                                  (const unsigned short*)0);
    // conv2: T1 = P(gx1), T2 = P(T1); pool fused (196 pool blocks FIRST)
    k_prop<<<pb, 256, 0, stream>>>(gx1, rowptr, csr_sw, T1);
    k_prop<<<pb, 256, 0, stream>>>(T1, rowptr, csr_sw, T2);
    k_convg<1, 2><<<196 + 97 * 16 + 12, 512, 0, stream>>>(gx1, T1, T2, W2t, b2f,
                                                          (unsigned short*)0,
                                                          batch32, psum, featb);
    // FC head: parallel split (512 + 256 blocks, short chains)
    k_fc1<<<512, 256, 0, stream>>>(psum, pcnt, fc1wf, fc1bf, hbuf);
    ChebModel_74380243632480_kernel<<<256, 256, 0, stream>>>(
        hbuf, fc2wf, fc2bf, (const unsigned int*)feature, d_out);
}

// Round 15
// 345.367 us; speedup vs baseline: 1.0263x; 1.0263x over previous
//
#include <hip/hip_runtime.h>
#include <hip/hip_bf16.h>

#define NNODES 50000
#define NEDGES 600000
#define NB 196     // ceil(NNODES/256)
#define NBKT 196   // coarse buckets (dst >> 8)
#define SB 192     // edge-pass blocks (hist + count + scatter)
#define SCH (NEDGES / SB)   // 3125 edges per block (exact)
#define STRIPS 782 // ceil(NNODES/64) row strips for conv

typedef short vs8 __attribute__((ext_vector_type(8)));
typedef float floatx4 __attribute__((ext_vector_type(4)));

__device__ __forceinline__ float us2f(unsigned short u) {
    unsigned int x = ((unsigned int)u) << 16;
    float f;
    __builtin_memcpy(&f, &x, 4);
    return f;
}
__device__ __forceinline__ unsigned short f2us(float f) {
    unsigned int x;
    __builtin_memcpy(&x, &f, 4);
    unsigned int r = x + 0x7fffu + ((x >> 16) & 1u);  // RNE
    return (unsigned short)(r >> 16);
}
__device__ __forceinline__ float ldf(const void* p, int i, int ff) {
    if (ff) return us2f(((const unsigned short*)p)[i]);
    return ((const float*)p)[i];
}
// inline dtype detection; every wave computes it from the first 256B of the
// edge list / feature — L2-hit broadcast, wave-uniform result.
__device__ __forceinline__ int detect_iflag(const int* ei) {
    int lane = threadIdx.x & 63;
    int odd1 = ei[2 * lane + 1];
    int odd2 = ei[128 + 2 * lane + 1];
    unsigned long long nz = __ballot(odd1 != 0 || odd2 != 0);
    return (nz == 0ULL) ? 1 : 0;
}
__device__ __forceinline__ int detect_fflag(const unsigned int* fw) {
    int lane = threadIdx.x & 63;
    unsigned int e = (fw[lane] >> 7) & 0xffu;
    unsigned long long h = __ballot(e > 100u && e < 160u);
    return (__popcll(h) > 40) ? 1 : 0;  // 1 = bf16 storage
}
// nontemporal 8B load of an (src, weight-bits) pair
__device__ __forceinline__ int2 ldnt_sw(const int2* p) {
    unsigned long long v =
        __builtin_nontemporal_load(reinterpret_cast<const unsigned long long*>(p));
    int2 r;
    r.x = (int)(unsigned int)(v & 0xffffffffULL);
    r.y = (int)(unsigned int)(v >> 32);
    return r;
}
// async global->LDS, 16B per lane; LDS dest = wave-uniform base + lane*16
__device__ __forceinline__ void gload_lds16(const unsigned short* g, unsigned short* l) {
    __builtin_amdgcn_global_load_lds(
        (const __attribute__((address_space(1))) unsigned int*)g,
        (__attribute__((address_space(3))) unsigned int*)l, 16, 0, 0);
}
// accumulate one weighted bf16x8 row chunk
__device__ __forceinline__ void accum8(float w, uint4 u, float& a0, float& a1,
                                       float& a2, float& a3, float& a4, float& a5,
                                       float& a6, float& a7) {
    a0 += w * us2f((unsigned short)(u.x & 0xffffu));
    a1 += w * us2f((unsigned short)(u.x >> 16));
    a2 += w * us2f((unsigned short)(u.y & 0xffffu));
    a3 += w * us2f((unsigned short)(u.y >> 16));
    a4 += w * us2f((unsigned short)(u.z & 0xffffu));
    a5 += w * us2f((unsigned short)(u.z >> 16));
    a6 += w * us2f((unsigned short)(u.w & 0xffffu));
    a7 += w * us2f((unsigned short)(u.w >> 16));
}

// canonicalize feature -> bf16 (16B/thread) + batch convert + psum zero
__global__ void k_featb(const void* src, const int* ei, const int* pb,
                        int* b32, float* psum, unsigned short* dst) {
    int i = blockIdx.x * 256 + threadIdx.x;
    int f = detect_iflag(ei);
    int ff = detect_fflag((const unsigned int*)src);
    if (i < NNODES) b32[i] = pb[((size_t)i) << f];
    if (i < 128 * 384) psum[i] = 0.f;
    if (i >= NNODES * 128 / 8) return;
    if (ff) {
        reinterpret_cast<uint4*>(dst)[i] = reinterpret_cast<const uint4*>(src)[i];
    } else {
        const float4* fs = reinterpret_cast<const float4*>(src);
        float4 a = fs[2 * i], b = fs[2 * i + 1];
        uint4 o;
        o.x = (unsigned int)f2us(a.x) | ((unsigned int)f2us(a.y) << 16);
        o.y = (unsigned int)f2us(a.z) | ((unsigned int)f2us(a.w) << 16);
        o.z = (unsigned int)f2us(b.x) | ((unsigned int)f2us(b.y) << 16);
        o.w = (unsigned int)f2us(b.z) | ((unsigned int)f2us(b.w) << 16);
        reinterpret_cast<uint4*>(dst)[i] = o;
    }
}

// ---- merged edge pass #1: out-degree histogram + coarse dst counts ----
__global__ __launch_bounds__(256) void k_deghist(const int* ei,
                                                 unsigned int* degpart, int* cntT) {
    __shared__ unsigned int h[25000];  // 100 KB
    __shared__ int c[NBKT];
    int t = threadIdx.x, blk = blockIdx.x;
    int f = detect_iflag(ei);
    for (int i = t; i < 25000; i += 256) h[i] = 0u;
    if (t < NBKT) c[t] = 0;
    __syncthreads();
    int e0 = blk * SCH;
    for (int j = t; j < SCH; j += 256) {
        int e = e0 + j;
        int s = ei[((size_t)e) << f];
        int d = ei[((size_t)(NEDGES + e)) << f];
        atomicAdd(&h[s >> 1], (s & 1) ? 65536u : 1u);
        atomicAdd(&c[d >> 8], 1);
    }
    __syncthreads();
    unsigned int* dp = degpart + (size_t)blk * 25000;
    for (int i = t; i < 25000; i += 256) dp[i] = h[i];
    if (t < NBKT) cntT[t * SB + blk] = c[t];
}

// merged: per-bucket parallel prefix (blocks 0..195) + degree reduce ->
// dinv (blocks 196..293). Independent work, one launch.
__global__ void k_mid(const unsigned int* degpart, float* dinv, int* cntT, int* btot) {
    int bid = blockIdx.x, t = threadIdx.x;
    if (bid < NBKT) {
        __shared__ int sh[256];
        int b = bid;
        int v = (t < SB) ? cntT[b * SB + t] : 0;
        sh[t] = v;
        __syncthreads();
        for (int off = 1; off < 256; off <<= 1) {
            int x = (t >= off) ? sh[t - off] : 0;
            __syncthreads();
            sh[t] += x;
            __syncthreads();
        }
        if (t < SB) cntT[b * SB + t] = sh[t] - v;  // exclusive prefix
        if (t == 255) btot[b] = sh[255];           // bucket total
    } else {
        int i = (bid - NBKT) * 256 + t;  // word index
        if (i >= 25000) return;
        unsigned int lo = 0, hi = 0;
        for (int b = 0; b < SB; ++b) {
            unsigned int p = degpart[(size_t)b * 25000 + i];
            lo += p & 0xffffu;
            hi += p >> 16;
        }
        dinv[2 * i] = lo ? rsqrtf((float)lo) : 0.f;
        dinv[2 * i + 1] = hi ? rsqrtf((float)hi) : 0.f;
    }
}

// one-block scan over 196 bucket totals -> gbase; pcnt binary searches.
__global__ void k_bscan2(const int* btot, int* gbase, const int* batch32,
                         int* pcnt, int* rowptr) {
    __shared__ int sh[256];
    int t = threadIdx.x;
    int v = (t < NBKT) ? btot[t] : 0;
    sh[t] = v;
    __syncthreads();
    for (int off = 1; off < 256; off <<= 1) {
        int x = (t >= off) ? sh[t - off] : 0;
        __syncthreads();
        sh[t] += x;
        __syncthreads();
    }
    if (t < NBKT) gbase[t] = sh[t] - v;
    if (t == 0) {
        gbase[NBKT] = NEDGES;
        rowptr[NNODES] = NEDGES;
    }
    if (t < 128) {
        int g = t;
        int lo = 0, hi = NNODES;
        while (lo < hi) { int mid = (lo + hi) >> 1; if (batch32[mid] < g) lo = mid + 1; else hi = mid; }
        int start = lo;
        hi = NNODES;
        while (lo < hi) { int mid = (lo + hi) >> 1; if (batch32[mid] <= g) lo = mid + 1; else hi = mid; }
        pcnt[g] = lo - start;
    }
}

// scatter edges into coarse buckets; cursor base = gbase + per-block prefix
__global__ void k_scat(const int* ei, const float* dinv,
                       const int* gbase, const int* cntT, int2* bkt) {
    __shared__ int cur[NBKT];
    int t = threadIdx.x, blk = blockIdx.x;
    int f = detect_iflag(ei);
    if (t < NBKT) cur[t] = gbase[t] + cntT[t * SB + blk];
    __syncthreads();
    int e0 = blk * SCH;
    for (int j = t; j < SCH; j += 256) {
        int e = e0 + j;
        int s = ei[((size_t)e) << f];
        int d = ei[((size_t)(NEDGES + e)) << f];
        float w = -dinv[s] * dinv[d];
        int slot = atomicAdd(&cur[d >> 8], 1);
        int wb;
        __builtin_memcpy(&wb, &w, 4);
        int2 v;
        v.x = s | ((d & 255) << 16);
        v.y = wb;
        bkt[slot] = v;
    }
}

// fine pass: one block per bucket; LDS 256-bin histogram + scan gives
// rowptr directly; LDS cursors give each edge its final CSR slot.
__global__ void k_csr(const int2* bkt, const int* gbase, int* rowptr, int2* csr_sw) {
    __shared__ int hist[256], scan[256], cur[256];
    int t = threadIdx.x, b = blockIdx.x;
    int beg = gbase[b], end = gbase[b + 1];
    int n = end - beg;
    hist[t] = 0;
    __syncthreads();
    for (int i = t; i < n; i += 256) {
        int bin = (bkt[beg + i].x >> 16) & 255;
        atomicAdd(&hist[bin], 1);
    }
    __syncthreads();
    int h = hist[t];
    scan[t] = h;
    __syncthreads();
    for (int off = 1; off < 256; off <<= 1) {
        int x = (t >= off) ? scan[t - off] : 0;
        __syncthreads();
        scan[t] += x;
        __syncthreads();
    }
    int excl = scan[t] - h;
    int node = b * 256 + t;
    if (node < NNODES) rowptr[node] = beg + excl;
    cur[t] = excl;
    __syncthreads();
    for (int i = t; i < n; i += 256) {
        int2 p = bkt[beg + i];
        int bin = (p.x >> 16) & 255;
        int slot = atomicAdd(&cur[bin], 1);
        int2 v;
        v.x = p.x & 0xffff;
        v.y = p.y;
        csr_sw[beg + slot] = v;
    }
}

// ALL weight prep in one launch (410624 elements)
__global__ void k_prepall(const void* W1, const void* W2, const void* b1, const void* b2,
                          const void* f1w, const void* f1b, const void* f2w, const void* f2b,
                          const unsigned int* fw, unsigned short* W1t, unsigned short* W2t,
                          float* b1f, float* b2f, float* f1wf, float* f1bf,
                          float* f2wf, float* f2bf) {
    int i = blockIdx.x * 256 + threadIdx.x;
    int ff = detect_fflag(fw);
    if (i < 49152) {
        int c = i >> 13;
        int rem = i & 8191;
        int cr = rem >> 6;
        int rem2 = rem & 63;
        int g = rem2 >> 3, j = rem2 & 7;
        int k = c * 64 + ((g ^ (cr & 7)) << 3) + j;
        int n = cr;
        float v;
        if (k < 128) v = ldf(W1, k * 128 + n, ff) - ldf(W1, (256 + k) * 128 + n, ff);
        else if (k < 256) v = ldf(W1, k * 128 + n, ff);
        else v = 2.f * ldf(W1, k * 128 + n, ff);
        W1t[i] = f2us(v);
        return;
    }
    i -= 49152;
    if (i < 98304) {
        int ct = i / 49152;
        int rem = i % 49152;
        int c = rem >> 13;
        int rem1 = rem & 8191;
        int cr = rem1 >> 6;
        int rem2 = rem1 & 63;
        int g = rem2 >> 3, j = rem2 & 7;
        int k = c * 64 + ((g ^ (cr & 7)) << 3) + j;
        int n = ct * 128 + cr;
        float v;
        if (k < 128) v = ldf(W2, k * 256 + n, ff) - ldf(W2, (256 + k) * 256 + n, ff);
        else if (k < 256) v = ldf(W2, k * 256 + n, ff);
        else v = 2.f * ldf(W2, k * 256 + n, ff);
        W2t[i] = f2us(v);
        return;
    }
    i -= 98304;
    if (i < 196608) { f1wf[i] = ldf(f1w, i, ff); return; }
    i -= 196608;
    if (i < 65536) { f2wf[i] = ldf(f2w, i, ff); return; }
    i -= 65536;
    if (i < 512) { f1bf[i] = ldf(f1b, i, ff); return; }
    i -= 512;
    if (i < 256) { b2f[i] = ldf(b2, i, ff); return; }
    i -= 256;
    if (i < 128) { b1f[i] = ldf(b1, i, ff); return; }
    i -= 128;
    if (i < 128) f2bf[i] = ldf(f2b, i, ff);
}

// out[n,:] = sum_{e into n} w_e * X[src_e,:]   (pure gather)
// UNIFORM clamped 8-deep loop at (256,6) — the empirical optimum of
// depth x occupancy x clamp-waste (R10/R13 vs R14: depth 12 regressed
// from gather overshoot + occupancy loss). OOB slots clamp index to
// end-1 (cache hit) and zero the weight.
__global__ __launch_bounds__(256, 6) void k_prop(const unsigned short* X,
                                                 const int* rowptr, const int2* csr_sw,
                                                 unsigned short* out) {
    int wvid = (blockIdx.x * blockDim.x + threadIdx.x) >> 6;
    int lane = threadIdx.x & 63;
    int q = lane >> 4;
    int ln = lane & 15;
    int node = wvid * 4 + q;
    if (node >= NNODES) return;
    int fo = ln * 8;  // short offset, 16 B per lane
    int beg = rowptr[node], end = rowptr[node + 1];
    float a0 = 0.f, a1 = 0.f, a2 = 0.f, a3 = 0.f;
    float a4 = 0.f, a5 = 0.f, a6 = 0.f, a7 = 0.f;
    for (int j = beg; j < end; j += 8) {
        int last = end - 1;
        int i1 = j + 1 < end ? j + 1 : last;
        int i2 = j + 2 < end ? j + 2 : last;
        int i3 = j + 3 < end ? j + 3 : last;
        int i4 = j + 4 < end ? j + 4 : last;
        int i5 = j + 5 < end ? j + 5 : last;
        int i6 = j + 6 < end ? j + 6 : last;
        int i7 = j + 7 < end ? j + 7 : last;
        int2 e0 = ldnt_sw(csr_sw + j);
        int2 e1 = ldnt_sw(csr_sw + i1);
        int2 e2 = ldnt_sw(csr_sw + i2);
        int2 e3 = ldnt_sw(csr_sw + i3);
        int2 e4 = ldnt_sw(csr_sw + i4);
        int2 e5 = ldnt_sw(csr_sw + i5);
        int2 e6 = ldnt_sw(csr_sw + i6);
        int2 e7 = ldnt_sw(csr_sw + i7);
        uint4 u0 = *reinterpret_cast<const uint4*>(X + (size_t)e0.x * 128 + fo);
        uint4 u1 = *reinterpret_cast<const uint4*>(X + (size_t)e1.x * 128 + fo);
        uint4 u2 = *reinterpret_cast<const uint4*>(X + (size_t)e2.x * 128 + fo);
        uint4 u3 = *reinterpret_cast<const uint4*>(X + (size_t)e3.x * 128 + fo);
        uint4 u4 = *reinterpret_cast<const uint4*>(X + (size_t)e4.x * 128 + fo);
        uint4 u5 = *reinterpret_cast<const uint4*>(X + (size_t)e5.x * 128 + fo);
        uint4 u6 = *reinterpret_cast<const uint4*>(X + (size_t)e6.x * 128 + fo);
        uint4 u7 = *reinterpret_cast<const uint4*>(X + (size_t)e7.x * 128 + fo);
        float w0, w1, w2, w3, w4, w5, w6, w7;
        __builtin_memcpy(&w0, &e0.y, 4);
        __builtin_memcpy(&w1, &e1.y, 4);
        __builtin_memcpy(&w2, &e2.y, 4);
        __builtin_memcpy(&w3, &e3.y, 4);
        __builtin_memcpy(&w4, &e4.y, 4);
        __builtin_memcpy(&w5, &e5.y, 4);
        __builtin_memcpy(&w6, &e6.y, 4);
        __builtin_memcpy(&w7, &e7.y, 4);
        w1 = (j + 1 < end) ? w1 : 0.f;
        w2 = (j + 2 < end) ? w2 : 0.f;
        w3 = (j + 3 < end) ? w3 : 0.f;
        w4 = (j + 4 < end) ? w4 : 0.f;
        w5 = (j + 5 < end) ? w5 : 0.f;
        w6 = (j + 6 < end) ? w6 : 0.f;
        w7 = (j + 7 < end) ? w7 : 0.f;
        accum8(w0, u0, a0, a1, a2, a3, a4, a5, a6, a7);
        accum8(w1, u1, a0, a1, a2, a3, a4, a5, a6, a7);
        accum8(w2, u2, a0, a1, a2, a3, a4, a5, a6, a7);
        accum8(w3, u3, a0, a1, a2, a3, a4, a5, a6, a7);
        accum8(w4, u4, a0, a1, a2, a3, a4, a5, a6, a7);
        accum8(w5, u5, a0, a1, a2, a3, a4, a5, a6, a7);
        accum8(w6, u6, a0, a1, a2, a3, a4, a5, a6, a7);
        accum8(w7, u7, a0, a1, a2, a3, a4, a5, a6, a7);
    }
    uint4 ov;
    ov.x = (unsigned int)f2us(a0) | ((unsigned int)f2us(a1) << 16);
    ov.y = (unsigned int)f2us(a2) | ((unsigned int)f2us(a3) << 16);
    ov.z = (unsigned int)f2us(a4) | ((unsigned int)f2us(a5) << 16);
    ov.w = (unsigned int)f2us(a6) | ((unsigned int)f2us(a7) << 16);
    *reinterpret_cast<uint4*>(out + (size_t)node * 128 + fo) = ov;
}

// ---- MFMA conv GEMM: 64x128 tile, 3 blocks/CU; pool blocks first ----
template <int POOL, int CT>
__global__ __launch_bounds__(512, 6) void k_convg(
    const unsigned short* seg0, const unsigned short* seg1, const unsigned short* seg2,
    const unsigned short* Wt, const float* bias, unsigned short* out,
    const int* batch32, float* psum, const unsigned short* featX) {
    __shared__ __align__(16) unsigned short a_lds[2][4096];  // 8 KB x2 (64r x 64k)
    __shared__ __align__(16) unsigned short b_lds[2][8192];  // 16 KB x2 (128c x 64k)
    __shared__ float sh_ps[POOL ? 1024 : 1];
    int tid = threadIdx.x;
    int bid = blockIdx.x;
    if (POOL) {
        if (bid < 196) {  // featb pooling blocks FIRST (overlap, not tail)
            int pb = bid;
            int col = tid & 127, qq = tid >> 7;  // qq 0..3, 4x64 = 256 nodes/block
            int nbeg = pb * 256 + qq * 64;
            if (nbeg < NNODES) {
                int nend = nbeg + 64;
                if (nend > NNODES) nend = NNODES;
                float run = 0.f;
                int curg = batch32[nbeg];
                for (int n = nbeg; n < nend; ++n) {
                    int g = batch32[n];
                    if (g != curg) {
                        atomicAdd(&psum[curg * 384 + 256 + col], run);
                        run = 0.f;
                        curg = g;
                    }
                    run += us2f(featX[(size_t)n * 128 + col]);
                }
                atomicAdd(&psum[curg * 384 + 256 + col], run);
            }
            return;
        }
        bid -= 196;
    }
    // XCD-grouped supertiles over 782 strips of 64 rows; ct-major within.
    int grp = 8 * CT;
    int main_blocks = 97 * grp;  // strips 0..775
    int r, ct;
    if (bid < main_blocks) {
        int g = bid / grp;
        int rem = bid - g * grp;
        ct = rem >> 3;
        r = g * 8 + (rem & 7);
    } else {
        int t = bid - main_blocks;  // tail strips 776..781
        r = 776 + (CT == 1 ? t : t % 6);
        ct = (CT == 1) ? 0 : t / 6;
    }
    int r0 = r * 64;
    const unsigned short* segs[3] = {seg0, seg1, seg2};
    int wv = tid >> 6, lane = tid & 63;
    int wm = wv >> 2, wn = wv & 3;  // 2M x 4N waves; wave tile 32r x 32c
    int m = lane & 15, kq = lane >> 4;
    if (POOL) { sh_ps[tid] = 0.f; sh_ps[tid + 512] = 0.f; }

    // stage K-step c: A = 8 chunks of 1KB (1/wave), B = 16 chunks (2/wave)
    auto STAGE = [&](int buf, int c) {
        const unsigned short* S = segs[c >> 1];
        int h = c & 1;
        {
            int q = wv;                       // A chunk 0..7
            int rl = q * 8 + (lane >> 3);     // local row 0..63
            int g = lane & 7;                 // granule 0..7
            int rowg = r0 + rl;
            if (rowg >= NNODES) rowg = NNODES - 1;
            gload_lds16(S + (size_t)rowg * 128 + h * 64 + ((g ^ (rl & 7)) << 3),
                        &a_lds[buf][q * 512]);
        }
#pragma unroll
        for (int p = 0; p < 2; ++p) {
            int q = wv * 2 + p;
            gload_lds16(Wt + (size_t)(ct * 6 + c) * 8192 + q * 512 + (lane << 3),
                        &b_lds[buf][q * 512]);
        }
    };

    floatx4 acc[2][2];
#pragma unroll
    for (int mt = 0; mt < 2; ++mt)
#pragma unroll
        for (int nt = 0; nt < 2; ++nt) {
            acc[mt][nt][0] = 0.f; acc[mt][nt][1] = 0.f;
            acc[mt][nt][2] = 0.f; acc[mt][nt][3] = 0.f;
        }

    STAGE(0, 0);
    __syncthreads();
    int buf = 0;
#pragma unroll
    for (int c = 0; c < 6; ++c) {
        if (c < 5) STAGE(buf ^ 1, c + 1);
        vs8 af[2], bfr[2];
#pragma unroll
        for (int kf = 0; kf < 2; ++kf) {
            int G = kf * 4 + kq;
#pragma unroll
            for (int mt = 0; mt < 2; ++mt) {
                int row = wm * 32 + mt * 16 + m;
                af[mt] = *reinterpret_cast<const vs8*>(
                    &a_lds[buf][row * 64 + ((G ^ (row & 7)) << 3)]);
            }
#pragma unroll
            for (int nt = 0; nt < 2; ++nt) {
                int cl = wn * 32 + nt * 16 + m;
                bfr[nt] = *reinterpret_cast<const vs8*>(
                    &b_lds[buf][cl * 64 + ((G ^ (cl & 7)) << 3)]);
            }
#pragma unroll
            for (int mt = 0; mt < 2; ++mt)
#pragma unroll
                for (int nt = 0; nt < 2; ++nt)
                    acc[mt][nt] = __builtin_amdgcn_mfma_f32_16x16x32_bf16(
                        af[mt], bfr[nt], acc[mt][nt], 0, 0, 0);
        }
        if (c < 5) {
            __syncthreads();
            buf ^= 1;
        }
    }

    if (POOL == 0) {
#pragma unroll
        for (int mt = 0; mt < 2; ++mt) {
            int rbase = r0 + wm * 32 + mt * 16 + kq * 4;
#pragma unroll
            for (int nt = 0; nt < 2; ++nt) {
                int col = wn * 32 + nt * 16 + m;
                float bv = bias[col];
#pragma unroll
                for (int i = 0; i < 4; ++i) {
                    int rw = rbase + i;
                    if (rw < NNODES) {
                        float v = acc[mt][nt][i] + bv;
                        v = v > 0.f ? v : 0.f;
                        out[(size_t)rw * 128 + col] = f2us(v);
                    }
                }
            }
        }
    } else {
        int g0 = batch32[r0];  // min graph in block (batch sorted)
#pragma unroll
        for (int mt = 0; mt < 2; ++mt) {
            int rbase = r0 + wm * 32 + mt * 16 + kq * 4;
            int gid[4];
#pragma unroll
            for (int i = 0; i < 4; ++i) {
                int rw = rbase + i;
                gid[i] = rw < NNODES ? batch32[rw] : -1;
            }
#pragma unroll
            for (int nt = 0; nt < 2; ++nt) {
                int cl = wn * 32 + nt * 16 + m;
                int col = ct * 128 + cl;
                float bv = bias[col];
                float run = 0.f;
                int curg = -1;
#pragma unroll
                for (int i = 0; i < 4; ++i) {
                    int g = gid[i];
                    if (g < 0) break;
                    float v = acc[mt][nt][i] + bv;
                    v = v > 0.f ? v : 0.f;
                    if (g != curg) {
                        if (curg >= 0) {
                            int gl = curg - g0;
                            if (gl >= 0 && gl < 8) atomicAdd(&sh_ps[gl * 128 + cl], run);
                            else atomicAdd(&psum[curg * 384 + col], run);
                        }
                        curg = g;
                        run = 0.f;
                    }
                    run += v;
                }
                if (curg >= 0) {
                    int gl = curg - g0;
                    if (gl >= 0 && gl < 8) atomicAdd(&sh_ps[gl * 128 + cl], run);
                    else atomicAdd(&psum[curg * 384 + col], run);
                }
            }
        }
        __syncthreads();
        for (int idx = tid; idx < 1024; idx += 512) {
            int gl = idx >> 7, cl = idx & 127;
            float v = sh_ps[idx];
            int gg = g0 + gl;
            if (v != 0.f && gg < 128) atomicAdd(&psum[(size_t)gg * 384 + ct * 128 + cl], v);
        }
    }
}

// FC1, parallelism-first: 512 blocks = (graph, 128-col slice), k split in
// halves of 192 -> per-thread chain 192 iters, LDS pair-reduce.
__global__ void k_fc1(const float* psum, const int* pcnt, const float* w,
                      const float* b, float* h) {
    __shared__ float ps[256];
    int g = blockIdx.x >> 2, slice = blockIdx.x & 3;
    int tid = threadIdx.x;
    int col = slice * 128 + (tid & 127);
    int half = tid >> 7;
    float a = 0.f;
    int k0 = half * 192;
    for (int k = k0; k < k0 + 192; ++k)
        a += psum[g * 384 + k] * w[k * 512 + col];
    ps[tid] = a;
    __syncthreads();
    if (tid < 128) {
        int c = pcnt[g];
        float inv = 1.f / (float)(c > 0 ? c : 1);
        float v = (ps[tid] + ps[tid + 128]) * inv + b[col];
        h[g * 512 + col] = v > 0.f ? v : 0.f;
    }
}

// FC2: 256 blocks = (graph, 64-col slice), k split in quarters of 128 ->
// chain 128 iters, LDS 4-way reduce. Carries the harness identifier name.
__global__ void ChebModel_74380243632480_kernel(
    const float* h, const float* w, const float* b, const unsigned int* fw,
    void* out) {
    __shared__ float ps[256];
    int g = blockIdx.x >> 1, slice = blockIdx.x & 1;
    int tid = threadIdx.x;
    int ff = detect_fflag(fw);
    int col = slice * 64 + (tid & 63);
    int qq = tid >> 6;
    float a = 0.f;
    int k0 = qq * 128;
    for (int k = k0; k < k0 + 128; ++k)
        a += h[g * 512 + k] * w[k * 128 + col];
    ps[tid] = a;
    __syncthreads();
    if (tid < 64) {
        float v = ps[tid] + ps[tid + 64] + ps[tid + 128] + ps[tid + 192] + b[col];
        if (ff) ((unsigned short*)out)[g * 128 + col] = f2us(v);
        else ((float*)out)[g * 128 + col] = v;
    }
}

extern "C" void kernel_launch(void* const* d_in, const int* in_sizes, int n_in,
                              void* d_out, int out_size, void* d_ws, size_t ws_size,
                              hipStream_t stream) {
    const void* feature = d_in[0];
    const int* edge_index = (const int*)d_in[1];
    const int* batch = (const int*)d_in[2];
    const void* W1 = d_in[3];
    const void* b1 = d_in[4];
    const void* W2 = d_in[5];
    const void* b2 = d_in[6];
    const void* fc1w = d_in[7];
    const void* fc1b = d_in[8];
    const void* fc2w = d_in[9];
    const void* fc2b = d_in[10];

    char* ws = (char*)d_ws;
    size_t off = 0;
    int* rowptr = (int*)(ws + off); off += ((size_t)(NNODES + 1) * 4 + 255) & ~(size_t)255;
    float* dinv = (float*)(ws + off); off += ((size_t)NNODES * 4 + 255) & ~(size_t)255;
    int* batch32 = (int*)(ws + off); off += ((size_t)NNODES * 4 + 255) & ~(size_t)255;
    int* gbase = (int*)(ws + off); off += 1024;
    int* cntT = (int*)(ws + off); off += ((size_t)SB * NBKT * 4 + 255) & ~(size_t)255;
    int* btot = (int*)(ws + off); off += 1024;
    int2* csr_sw = (int2*)(ws + off); off += ((size_t)NEDGES * 8 + 255) & ~(size_t)255;
    unsigned short* featb = (unsigned short*)(ws + off); off += ((size_t)NNODES * 128 * 2 + 255) & ~(size_t)255;
    unsigned short* T1 = (unsigned short*)(ws + off); off += ((size_t)NNODES * 128 * 2 + 255) & ~(size_t)255;
    unsigned short* T2 = (unsigned short*)(ws + off); off += ((size_t)NNODES * 128 * 2 + 255) & ~(size_t)255;
    unsigned short* gx1 = (unsigned short*)(ws + off); off += ((size_t)NNODES * 128 * 2 + 255) & ~(size_t)255;
    unsigned short* W1t = (unsigned short*)(ws + off); off += ((size_t)49152 * 2 + 255) & ~(size_t)255;
    unsigned short* W2t = (unsigned short*)(ws + off); off += ((size_t)98304 * 2 + 255) & ~(size_t)255;
    float* b1f = (float*)(ws + off); off += 1024;
    float* b2f = (float*)(ws + off); off += 1024;
    float* fc1wf = (float*)(ws + off); off += ((size_t)196608 * 4 + 255) & ~(size_t)255;
    float* fc1bf = (float*)(ws + off); off += 2048;
    float* fc2wf = (float*)(ws + off); off += ((size_t)65536 * 4 + 255) & ~(size_t)255;
    float* fc2bf = (float*)(ws + off); off += 1024;
    float* psum = (float*)(ws + off); off += ((size_t)128 * 384 * 4 + 255) & ~(size_t)255;
    int* pcnt = (int*)(ws + off); off += 1024;
    float* hbuf = (float*)(ws + off); off += ((size_t)128 * 512 * 4 + 255) & ~(size_t)255;

    // sort scratch aliases the T1/T2/gx1 feature buffers (all first written
    // only after preprocessing is fully done):
    int2* bkt = (int2*)T1;                       // 4.8 MB <= 12.8 MB
    unsigned int* degpart = (unsigned int*)T2;   // SB*25000*4 = 19.2 MB <= T2+gx1 (25.6 MB)

    k_featb<<<(NNODES * 128 / 8 + 255) / 256, 256, 0, stream>>>(
        feature, edge_index, batch, batch32, psum, featb);
    k_deghist<<<SB, 256, 0, stream>>>(edge_index, degpart, cntT);
    k_mid<<<NBKT + (25000 + 255) / 256, 256, 0, stream>>>(degpart, dinv, cntT, btot);
    k_bscan2<<<1, 256, 0, stream>>>(btot, gbase, batch32, pcnt, rowptr);
    k_scat<<<SB, 256, 0, stream>>>(edge_index, dinv, gbase, cntT, bkt);
    k_csr<<<NBKT, 256, 0, stream>>>(bkt, gbase, rowptr, csr_sw);
    k_prepall<<<(410624 + 255) / 256, 256, 0, stream>>>(
        W1, W2, b1, b2, fc1w, fc1b, fc2w, fc2b, (const unsigned int*)feature,
        W1t, W2t, b1f, b2f, fc1wf, fc1bf, fc2wf, fc2bf);

    int pb = ((NNODES + 3) / 4 * 64 + 255) / 256;  // 3125 blocks, 4 nodes/wave
    // conv1: T1 = P(featb), T2 = P(T1); gx1 = relu([featb|T1|T2] @ foldedW1 + b1)
    k_prop<<<pb, 256, 0, stream>>>(featb, rowptr, csr_sw, T1);
    k_prop<<<pb, 256, 0, stream>>>(T1, rowptr, csr_sw, T2);
    k_convg<0, 1><<<97 * 8 + 6, 512, 0, stream>>>(featb, T1, T2, W1t, b1f, gx1,
                                                  (const int*)0, (float*)0,
                                                  (const unsigned short*)0);
    // conv2: T1 = P(gx1), T2 = P(T1); pool fused (196 pool blocks FIRST)
    k_prop<<<pb, 256, 0, stream>>>(gx1, rowptr, csr_sw, T1);
    k_prop<<<pb, 256, 0, stream>>>(T1, rowptr, csr_sw, T2);
    k_convg<1, 2><<<196 + 97 * 16 + 12, 512, 0, stream>>>(gx1, T1, T2, W2t, b2f,
                                                          (unsigned short*)0,
                                                          batch32, psum, featb);
    // FC head: parallel split (512 + 256 blocks, short chains)
    k_fc1<<<512, 256, 0, stream>>>(psum, pcnt, fc1wf, fc1bf, hbuf);
    ChebModel_74380243632480_kernel<<<256, 256, 0, stream>>>(
        hbuf, fc2wf, fc2bf, (const unsigned int*)feature, d_out);
}